// Round 1
// baseline (337.352 us; speedup 1.0000x reference)
//
#include <hip/hip_runtime.h>
#include <stdint.h>

typedef float  f32x4  __attribute__((ext_vector_type(4)));
typedef short  bf16x8 __attribute__((ext_vector_type(8)));

#define NHW 401408.0   // 32*112*112

__device__ __forceinline__ ushort f2bf(float f) {
  uint32_t u = __float_as_uint(f);
  uint32_t r = u + 0x7FFFu + ((u >> 16) & 1u);   // RNE
  return (ushort)(r >> 16);
}

// ---- K0: W[o][c][3][3] fp32 -> bf16, global layout [tap][o][c ^ ((o&7)<<3)]
// (pre-swizzled image of the conv kernel's B-LDS, enabling a linear copy)
__global__ __launch_bounds__(256) void prep_weights(const float* __restrict__ Wg,
                                                    ushort* __restrict__ Wswz) {
  int i = blockIdx.x * 256 + threadIdx.x;    // 9*64*64 = 36864 threads
  int tap = i >> 12;
  int o   = (i >> 6) & 63;
  int c   = i & 63;
  float w = Wg[(o * 64 + c) * 9 + tap];
  Wswz[tap * 4096 + o * 64 + (c ^ ((o & 7) << 3))] = f2bf(w);
}

// ---- K1: per-channel sum / sumsq in fp64 (block = one (n,c) plane)
__global__ __launch_bounds__(256) void stats_kernel(const float* __restrict__ x,
                                                    double* __restrict__ sums) {
  int blk = blockIdx.x;                       // n*64 + c
  const float4* p = (const float4*)(x + (size_t)blk * 12544);
  double s = 0.0, q = 0.0;
  for (int i = threadIdx.x; i < 3136; i += 256) {
    float4 v = p[i];
    double a = v.x, b = v.y, cc = v.z, d = v.w;
    s += a + b + cc + d;
    q += a * a + b * b + cc * cc + d * d;
  }
#pragma unroll
  for (int off = 32; off > 0; off >>= 1) {
    s += __shfl_down(s, off);
    q += __shfl_down(q, off);
  }
  __shared__ double ls[8];
  int wv = threadIdx.x >> 6;
  if ((threadIdx.x & 63) == 0) { ls[wv] = s; ls[4 + wv] = q; }
  __syncthreads();
  if (threadIdx.x == 0) {
    double S = ls[0] + ls[1] + ls[2] + ls[3];
    double Q = ls[4] + ls[5] + ls[6] + ls[7];
    int c = blk & 63;
    atomicAdd(&sums[c], S);
    atomicAdd(&sums[64 + c], Q);
  }
}

// ---- K2: mean/istd -> per-channel affine: xbn = fma(x, a, d)
__global__ void finalize_kernel(const double* __restrict__ sums,
                                const float* __restrict__ gamma,
                                const float* __restrict__ beta,
                                float* __restrict__ ad) {
  int c = threadIdx.x;                        // 64 threads
  double mean = sums[c] / NHW;
  double var  = sums[64 + c] / NHW - mean * mean;
  double istd = 1.0 / sqrt(var + 1e-4);
  double a = (double)gamma[c] * istd;
  double d = (double)beta[c] - mean * a;
  ad[c]      = (float)a;
  ad[64 + c] = (float)d;
}

// ---- K3: fused binarize + implicit-GEMM conv + bias + relu
// block = (n, 16x16 output tile), 256 threads = 4 waves, 1 block/CU.
// LDS: A = signs [sp=sh*18+sw][c] bf16, swizzled (sw&7)<<4  : 41472 B
//      B = weights [tap][o][c] bf16, swizzled (o&7)<<4      : 73728 B
#define LDS_A     41472
#define LDS_TOTAL (41472 + 73728)

extern __shared__ __align__(16) char smem[];

__global__ __launch_bounds__(256, 1) void conv_kernel(
    const float* __restrict__ x, const float* __restrict__ ad,
    const ushort* __restrict__ Wswz, const float* __restrict__ bias,
    float* __restrict__ out) {
  const int tid  = threadIdx.x;
  const int lane = tid & 63;
  const int wv   = tid >> 6;
  const int n    = blockIdx.y;
  const int th   = blockIdx.x / 7;
  const int tw   = blockIdx.x - th * 7;
  const int h0 = th * 16, w0 = tw * 16;

  // stage B: linear copy of the pre-swizzled weight image (L2-resident)
  {
    const float4* src = (const float4*)Wswz;
    float4* dst = (float4*)(smem + LDS_A);
#pragma unroll
    for (int j = 0; j < 18; ++j) dst[tid + j * 256] = src[tid + j * 256];
  }
  // stage A: gather x (lane = channel -> L1-cached lines), binarize, transpose into LDS
  {
    const int c  = tid & 63;
    const int rg = tid >> 6;
    const float a_c = ad[c];
    const float d_c = ad[64 + c];
    const float* xc = x + ((size_t)(n * 64 + c)) * 12544;
    ushort* Au = (ushort*)smem;
    for (int r = rg; r < 18; r += 4) {
      int gh = h0 - 1 + r;
      bool hok = (unsigned)gh < 112u;
      const float* xrow = xc + gh * 112;
      ushort* rowp = Au + r * (18 * 64);
#pragma unroll
      for (int sw = 0; sw < 18; ++sw) {
        int gw = w0 - 1 + sw;
        ushort v = 0;
        if (hok && (unsigned)gw < 112u) {
          float t = fmaf(xrow[gw], a_c, d_c);
          v = (t > 0.0f) ? (ushort)0x3F80 : ((t < 0.0f) ? (ushort)0xBF80 : (ushort)0);
        }
        rowp[sw * 64 + (c ^ ((sw & 7) << 3))] = v;   // lanes span c: conflict-free
      }
    }
  }
  __syncthreads();

  // main loop: K = tap*64 + c (576), 18 steps of K=32
  f32x4 acc[4][4] = {};
  const int pw   = lane & 15;          // A: M-row = output w ; B: o-within-frag
  const int kg   = lane >> 4;          // k-group
  const int oswz = (pw & 7) << 4;
  const char* As = smem;
  const char* Bs = smem + LDS_A;

#pragma unroll
  for (int tap = 0; tap < 9; ++tap) {
    const int kh = tap / 3, kw = tap % 3;
    const int sw = pw + kw;
    const int aswz = (sw & 7) << 4;
#pragma unroll
    for (int half = 0; half < 2; ++half) {
      const int cb2 = half * 64 + kg * 16;   // byte offset of c-base within 128B row
      bf16x8 af[4], bfr[4];
#pragma unroll
      for (int rf = 0; rf < 4; ++rf) {
        int sh = 4 * wv + rf + kh;
        af[rf] = *(const bf16x8*)(As + (sh * 18 + sw) * 128 + (cb2 ^ aswz));
      }
#pragma unroll
      for (int cf = 0; cf < 4; ++cf) {
        bfr[cf] = *(const bf16x8*)(Bs + tap * 8192 + (cf * 16 + pw) * 128 + (cb2 ^ oswz));
      }
#pragma unroll
      for (int rf = 0; rf < 4; ++rf)
#pragma unroll
        for (int cf = 0; cf < 4; ++cf)
          acc[rf][cf] = __builtin_amdgcn_mfma_f32_16x16x32_bf16(af[rf], bfr[cf],
                                                                acc[rf][cf], 0, 0, 0);
    }
  }
  __syncthreads();   // all waves done reading A/B before patches overwrite LDS

  // epilogue: bias+relu, transpose via per-wave LDS patch (pad 65), coalesced NCHW stores
  float* patch = (float*)smem + wv * (64 * 65);
  float bv[4];
#pragma unroll
  for (int cf = 0; cf < 4; ++cf) bv[cf] = bias[cf * 16 + pw];
#pragma unroll
  for (int rf = 0; rf < 4; ++rf)
#pragma unroll
    for (int cf = 0; cf < 4; ++cf)
#pragma unroll
      for (int r = 0; r < 4; ++r) {
        float v = acc[rf][cf][r] + bv[cf];
        // D-frag: col(o) = lane&15, row(pw) = (lane>>4)*4 + r ; p_local = rf*16 + row
        patch[(cf * 16 + pw) * 65 + rf * 16 + kg * 4 + r] = fmaxf(v, 0.0f);
      }
  // same-wave RAW through LDS; compiler inserts lgkmcnt
  size_t ob = (((size_t)n * 64) * 112 + (h0 + wv * 4 + kg)) * 112 + w0 + pw;
#pragma unroll 4
  for (int o = 0; o < 64; ++o) {
    out[ob + (size_t)o * 12544] = patch[o * 65 + kg * 16 + pw];
  }
}

extern "C" void kernel_launch(void* const* d_in, const int* in_sizes, int n_in,
                              void* d_out, int out_size, void* d_ws, size_t ws_size,
                              hipStream_t stream) {
  (void)in_sizes; (void)n_in; (void)out_size; (void)ws_size;
  const float* x     = (const float*)d_in[0];
  const float* gamma = (const float*)d_in[1];
  const float* beta  = (const float*)d_in[2];
  const float* Wg    = (const float*)d_in[3];
  const float* bias  = (const float*)d_in[4];
  float* out = (float*)d_out;

  char* ws = (char*)d_ws;
  float*  ad   = (float*)ws;              // 128 f32  : a[c], d[c]
  double* sums = (double*)(ws + 512);     // 128 f64  : sum[c], sumsq[c]
  ushort* Wswz = (ushort*)(ws + 1536);    // 73728 B  : swizzled bf16 weights

  hipMemsetAsync(sums, 0, 128 * sizeof(double), stream);
  prep_weights<<<dim3(144), dim3(256), 0, stream>>>(Wg, Wswz);
  stats_kernel<<<dim3(2048), dim3(256), 0, stream>>>(x, sums);
  finalize_kernel<<<dim3(1), dim3(64), 0, stream>>>(sums, gamma, beta, ad);

  hipFuncSetAttribute(reinterpret_cast<const void*>(conv_kernel),
                      hipFuncAttributeMaxDynamicSharedMemorySize, LDS_TOTAL);
  conv_kernel<<<dim3(49, 32), dim3(256), LDS_TOTAL, stream>>>(x, ad, Wswz, bias, out);
}

// Round 2
// 314.929 us; speedup vs baseline: 1.0712x; 1.0712x over previous
//
#include <hip/hip_runtime.h>
#include <stdint.h>

typedef float  f32x4  __attribute__((ext_vector_type(4)));
typedef short  bf16x8 __attribute__((ext_vector_type(8)));

#define NHW 401408.0   // 32*112*112

__device__ __forceinline__ ushort f2bf(float f) {
  uint32_t u = __float_as_uint(f);
  uint32_t r = u + 0x7FFFu + ((u >> 16) & 1u);   // RNE
  return (ushort)(r >> 16);
}

// ---- K0: W[o][c][3][3] fp32 -> bf16 in MFMA-fragment order:
// Wfrag[((tap*2+half)*4+cf)*512 + lane*8 + j],  lane = kg*16+pw,
// holding W[o=cf*16+pw][c = half*32+kg*8+j].  One coalesced dwordx4 per
// (tap,half,cf) fragment load in the conv kernel (no LDS needed for B).
__global__ __launch_bounds__(256) void prep_weights(const float* __restrict__ Wg,
                                                    ushort* __restrict__ Wfrag) {
  int i = blockIdx.x * 256 + threadIdx.x;    // 9*64*64 = 36864 threads
  int tap = i >> 12;
  int o   = (i >> 6) & 63;
  int c   = i & 63;
  float w = Wg[(o * 64 + c) * 9 + tap];
  int cf = o >> 4, pw = o & 15;
  int half = c >> 5, kg = (c >> 3) & 3, j = c & 7;
  Wfrag[(((tap * 2 + half) * 4 + cf) << 9) + ((kg * 16 + pw) << 3) + j] = f2bf(w);
}

// ---- K1: per-channel sum / sumsq (f32 per-thread partials, fp64 atomics)
__global__ __launch_bounds__(256) void stats_kernel(const float* __restrict__ x,
                                                    double* __restrict__ sums) {
  int blk = blockIdx.x;                       // n*64 + c
  const float4* p = (const float4*)(x + (size_t)blk * 12544);
  float s = 0.f, q = 0.f;
  for (int i = threadIdx.x; i < 3136; i += 256) {
    float4 v = p[i];
    s += (v.x + v.y) + (v.z + v.w);
    q += v.x * v.x + v.y * v.y + v.z * v.z + v.w * v.w;
  }
#pragma unroll
  for (int off = 32; off > 0; off >>= 1) {
    s += __shfl_down(s, off);
    q += __shfl_down(q, off);
  }
  __shared__ float ls[8];
  int wv = threadIdx.x >> 6;
  if ((threadIdx.x & 63) == 0) { ls[wv] = s; ls[4 + wv] = q; }
  __syncthreads();
  if (threadIdx.x == 0) {
    double S = (double)ls[0] + ls[1] + ls[2] + ls[3];
    double Q = (double)ls[4] + ls[5] + ls[6] + ls[7];
    int c = blk & 63;
    atomicAdd(&sums[c], S);
    atomicAdd(&sums[64 + c], Q);
  }
}

// ---- K2: mean/istd -> per-channel affine: xbn = fma(x, a, d)
__global__ void finalize_kernel(const double* __restrict__ sums,
                                const float* __restrict__ gamma,
                                const float* __restrict__ beta,
                                float* __restrict__ ad) {
  int c = threadIdx.x;                        // 64 threads
  double mean = sums[c] / NHW;
  double var  = sums[64 + c] / NHW - mean * mean;
  double istd = 1.0 / sqrt(var + 1e-4);
  double a = (double)gamma[c] * istd;
  double d = (double)beta[c] - mean * a;
  ad[c]      = (float)a;
  ad[64 + c] = (float)d;
}

// ---- K3: fused binarize + implicit-GEMM conv + bias + relu
// block = (n, 16x16 tile), 256 thr = 4 waves. LDS = A-signs only: 41472 B
// -> 3 blocks/CU (12 waves/CU). B-fragments come straight from global (L1/L2).
__global__ __launch_bounds__(256, 3) void conv_kernel(
    const float* __restrict__ x, const float* __restrict__ ad,
    const ushort* __restrict__ Wfrag, const float* __restrict__ bias,
    float* __restrict__ out) {
  __shared__ __align__(16) char smem[41472];   // A: [sp=sh*18+sw][c] bf16, swz (sw&7)<<4

  const int tid  = threadIdx.x;
  const int lane = tid & 63;
  const int wv   = tid >> 6;

  // XCD-aware swizzle: 1568 blocks = 8 XCDs x 196 contiguous tiles
  int w_id = (blockIdx.x & 7) * 196 + (blockIdx.x >> 3);
  const int n  = w_id / 49;
  const int t  = w_id - n * 49;
  const int th = t / 7;
  const int tw = t - th * 7;
  const int h0 = th * 16, w0 = tw * 16;

  // ---- stage A: gather x (lane = channel), binarize, transpose into LDS
  {
    const int c  = tid & 63;
    const int rg = tid >> 6;
    const float a_c = ad[c];
    const float d_c = ad[64 + c];
    const float* xc = x + ((size_t)(n * 64 + c)) * 12544;
    ushort* Au = (ushort*)smem;
    const bool interior = (tw >= 1) && (tw <= 5);
    for (int r = rg; r < 18; r += 4) {
      int gh = h0 - 1 + r;
      bool hok = (unsigned)gh < 112u;
      ushort* rowp = Au + r * (18 * 64);
      if (!hok) {
#pragma unroll
        for (int sw = 0; sw < 18; ++sw) rowp[sw * 64 + (c ^ ((sw & 7) << 3))] = 0;
      } else if (interior) {
        // aligned vector path: 6x float4 covering w0-4 .. w0+19
        const f32x4* vp = (const f32x4*)(xc + gh * 112 + (w0 - 4));
        float f[24];
#pragma unroll
        for (int k = 0; k < 6; ++k) {
          f32x4 v = vp[k];
          f[4 * k] = v[0]; f[4 * k + 1] = v[1]; f[4 * k + 2] = v[2]; f[4 * k + 3] = v[3];
        }
#pragma unroll
        for (int sw = 0; sw < 18; ++sw) {
          float tt = fmaf(f[3 + sw], a_c, d_c);
          ushort v = (tt > 0.f) ? (ushort)0x3F80 : ((tt < 0.f) ? (ushort)0xBF80 : (ushort)0);
          rowp[sw * 64 + (c ^ ((sw & 7) << 3))] = v;
        }
      } else {
        const float* xrow = xc + gh * 112;
#pragma unroll
        for (int sw = 0; sw < 18; ++sw) {
          int gw = w0 - 1 + sw;
          ushort v = 0;
          if ((unsigned)gw < 112u) {
            float tt = fmaf(xrow[gw], a_c, d_c);
            v = (tt > 0.f) ? (ushort)0x3F80 : ((tt < 0.f) ? (ushort)0xBF80 : (ushort)0);
          }
          rowp[sw * 64 + (c ^ ((sw & 7) << 3))] = v;
        }
      }
    }
  }
  __syncthreads();

  // ---- main loop: K = tap*64 + c (576), 18 half-steps of K=32
  f32x4 acc[4][4] = {};
  const int pw = lane & 15;            // A: M = output w ; B/D: o-within-frag
  const int kg = lane >> 4;            // k-group
  const char* As = smem;

#pragma unroll
  for (int tap = 0; tap < 9; ++tap) {
    const int kh = tap / 3, kw = tap % 3;
    const int sw = pw + kw;
    const int aswz = (sw & 7) << 4;
#pragma unroll
    for (int half = 0; half < 2; ++half) {
      const int cb2 = half * 64 + kg * 16;   // byte offset of c-base in 128B row
      bf16x8 af[4], bfr[4];
#pragma unroll
      for (int rf = 0; rf < 4; ++rf) {
        int sh = 4 * wv + rf + kh;
        af[rf] = *(const bf16x8*)(As + (sh * 18 + sw) * 128 + (cb2 ^ aswz));
      }
#pragma unroll
      for (int cf = 0; cf < 4; ++cf) {
        bfr[cf] = *(const bf16x8*)(Wfrag + (((tap * 2 + half) * 4 + cf) << 9) + (lane << 3));
      }
#pragma unroll
      for (int rf = 0; rf < 4; ++rf)
#pragma unroll
        for (int cf = 0; cf < 4; ++cf)
          acc[rf][cf] = __builtin_amdgcn_mfma_f32_16x16x32_bf16(af[rf], bfr[cf],
                                                                acc[rf][cf], 0, 0, 0);
    }
  }
  __syncthreads();   // all waves done reading A before patches overwrite LDS

  // ---- epilogue: bias+relu; per-rf transpose patch (64 o x 17 w floats,
  // ping-pong x2 per wave = 34816 B total, fits in the A region)
  float bv[4];
#pragma unroll
  for (int cf = 0; cf < 4; ++cf) bv[cf] = bias[cf * 16 + pw];
#pragma unroll
  for (int rf = 0; rf < 4; ++rf) {
    float* patch = (float*)smem + (wv * 2 + (rf & 1)) * (64 * 17);
#pragma unroll
    for (int cf = 0; cf < 4; ++cf)
#pragma unroll
      for (int r = 0; r < 4; ++r) {
        // D: col(o) = lane&15, row(w) = kg*4 + r
        float v = acc[rf][cf][r] + bv[cf];
        patch[(cf * 16 + pw) * 17 + kg * 4 + r] = fmaxf(v, 0.f);
      }
    int row = h0 + 4 * wv + rf;
    size_t ob = ((size_t)n * 64 + kg) * 12544 + (size_t)row * 112 + w0 + pw;
#pragma unroll
    for (int j = 0; j < 16; ++j) {   // o = j*4 + kg -> 64B-coalesced segments
      out[ob + (size_t)(j * 4) * 12544] = patch[(j * 4 + kg) * 17 + pw];
    }
  }
}

extern "C" void kernel_launch(void* const* d_in, const int* in_sizes, int n_in,
                              void* d_out, int out_size, void* d_ws, size_t ws_size,
                              hipStream_t stream) {
  (void)in_sizes; (void)n_in; (void)out_size; (void)ws_size;
  const float* x     = (const float*)d_in[0];
  const float* gamma = (const float*)d_in[1];
  const float* beta  = (const float*)d_in[2];
  const float* Wg    = (const float*)d_in[3];
  const float* bias  = (const float*)d_in[4];
  float* out = (float*)d_out;

  char* ws = (char*)d_ws;
  float*  ad    = (float*)ws;              // 128 f32  : a[c], d[c]
  double* sums  = (double*)(ws + 512);     // 128 f64  : sum[c], sumsq[c]
  ushort* Wfrag = (ushort*)(ws + 1536);    // 73728 B  : fragment-ordered bf16 weights

  hipMemsetAsync(sums, 0, 128 * sizeof(double), stream);
  prep_weights<<<dim3(144), dim3(256), 0, stream>>>(Wg, Wfrag);
  stats_kernel<<<dim3(2048), dim3(256), 0, stream>>>(x, sums);
  finalize_kernel<<<dim3(1), dim3(64), 0, stream>>>(sums, gamma, beta, ad);
  conv_kernel<<<dim3(1568), dim3(256), 0, stream>>>(x, ad, Wfrag, bias, out);
}

// Round 3
// 296.676 us; speedup vs baseline: 1.1371x; 1.0615x over previous
//
#include <hip/hip_runtime.h>
#include <stdint.h>

typedef float    f32x4  __attribute__((ext_vector_type(4)));
typedef short    bf16x8 __attribute__((ext_vector_type(8)));
typedef uint32_t u32;

#define NHW 401408.0   // 32*112*112

__device__ __forceinline__ ushort f2bf(float f) {
  uint32_t u = __float_as_uint(f);
  uint32_t r = u + 0x7FFFu + ((u >> 16) & 1u);   // RNE
  return (ushort)(r >> 16);
}

__device__ __forceinline__ void gload_lds16(const void* g, void* l) {
  typedef __attribute__((address_space(1))) const u32 gu32;
  typedef __attribute__((address_space(3))) u32 lu32;
  __builtin_amdgcn_global_load_lds((gu32*)g, (lu32*)l, 16, 0, 0);
}

// ---- K0: W[o][c][3][3] fp32 -> bf16 in MFMA A-fragment order:
// Wfrag[((tap*2+half)*4+of)*512 + (kg*16+pw)*8 + j] = W[of*16+pw][half*32+kg*8+j]
__global__ __launch_bounds__(256) void prep_weights(const float* __restrict__ Wg,
                                                    ushort* __restrict__ Wfrag) {
  int i = blockIdx.x * 256 + threadIdx.x;    // 36864
  int tap = i >> 12;
  int o   = (i >> 6) & 63;
  int c   = i & 63;
  float w = Wg[(o * 64 + c) * 9 + tap];
  int of = o >> 4, pw = o & 15;
  int half = c >> 5, kg = (c >> 3) & 3, j = c & 7;
  Wfrag[(((tap * 2 + half) * 4 + of) << 9) + ((kg * 16 + pw) << 3) + j] = f2bf(w);
}

// ---- K1: per-channel sum / sumsq
__global__ __launch_bounds__(256) void stats_kernel(const float* __restrict__ x,
                                                    double* __restrict__ sums) {
  int blk = blockIdx.x;                       // n*64 + c
  const float4* p = (const float4*)(x + (size_t)blk * 12544);
  float s = 0.f, q = 0.f;
  for (int i = threadIdx.x; i < 3136; i += 256) {
    float4 v = p[i];
    s += (v.x + v.y) + (v.z + v.w);
    q += v.x * v.x + v.y * v.y + v.z * v.z + v.w * v.w;
  }
#pragma unroll
  for (int off = 32; off > 0; off >>= 1) {
    s += __shfl_down(s, off);
    q += __shfl_down(q, off);
  }
  __shared__ float ls[8];
  int wv = threadIdx.x >> 6;
  if ((threadIdx.x & 63) == 0) { ls[wv] = s; ls[4 + wv] = q; }
  __syncthreads();
  if (threadIdx.x == 0) {
    double S = (double)ls[0] + ls[1] + ls[2] + ls[3];
    double Q = (double)ls[4] + ls[5] + ls[6] + ls[7];
    int c = blk & 63;
    atomicAdd(&sums[c], S);
    atomicAdd(&sums[64 + c], Q);
  }
}

// ---- K2: mean/istd -> per-channel affine: xbn = fma(x, a, d)
__global__ void finalize_kernel(const double* __restrict__ sums,
                                const float* __restrict__ gamma,
                                const float* __restrict__ beta,
                                float* __restrict__ ad) {
  int c = threadIdx.x;                        // 64 threads
  double mean = sums[c] / NHW;
  double var  = sums[64 + c] / NHW - mean * mean;
  double istd = 1.0 / sqrt(var + 1e-4);
  double a = (double)gamma[c] * istd;
  double d = (double)beta[c] - mean * a;
  ad[c]      = (float)a;
  ad[64 + c] = (float)d;
}

// ---- K3: binarize + NCHW->NHWC transpose, w-padded (wp=w+1, 114 slots),
// global layout signs[n][h][wp][c ^ ((wp&7)<<3)] bf16; wp=0,113 zeroed.
__global__ __launch_bounds__(256) void binarize_kernel(const float* __restrict__ x,
                                                       const float* __restrict__ ad,
                                                       ushort* __restrict__ signs) {
  __shared__ ushort ls[112 * 64];
  const int n = blockIdx.y, h = blockIdx.x;
  const int t = threadIdx.x;
  const int c = t >> 2, q = t & 3;
  const float a_c = ad[c], d_c = ad[64 + c];
  const f32x4* src = (const f32x4*)(x + (size_t)(n * 64 + c) * 12544 + h * 112 + q * 28);
#pragma unroll
  for (int i = 0; i < 7; ++i) {
    f32x4 v = src[i];
#pragma unroll
    for (int k = 0; k < 4; ++k) {
      float tt = fmaf(v[k], a_c, d_c);
      ushort s = (tt > 0.f) ? (ushort)0x3F80 : ((tt < 0.f) ? (ushort)0xBF80 : (ushort)0);
      int w = q * 28 + i * 4 + k;
      ls[w * 64 + (c ^ (((w + 1) & 7) << 3))] = s;
    }
  }
  __syncthreads();
  uint4* grow = (uint4*)(signs + (size_t)(n * 112 + h) * 114 * 64);
  const uint4* lsv = (const uint4*)ls;
  uint4 z = {0, 0, 0, 0};
  if (t < 8) grow[t] = z;                  // wp=0 border
  else if (t < 16) grow[904 + t - 8] = z;  // wp=113 border
  for (int i = t; i < 896; i += 256) grow[8 + i] = lsv[i];
}

// ---- K4: conv = implicit GEMM over pre-binarized signs
// block = 16x16 output tile, 4 waves; LDS = halo 18 rows x 2304B = 41472 -> 3 blk/CU
#define ROWB 2304
__global__ __launch_bounds__(256, 3) void conv_kernel(
    const ushort* __restrict__ signs, const ushort* __restrict__ Wfrag,
    const float* __restrict__ bias, float* __restrict__ out) {
  __shared__ __align__(16) char smem[18 * ROWB];
  const int tid = threadIdx.x, lane = tid & 63, wv = tid >> 6;
  const int w_id = (blockIdx.x & 7) * 196 + (blockIdx.x >> 3);   // 1568 = 8*196
  const int n = w_id / 49, t = w_id - n * 49;
  const int th = t / 7, tw = t - th * 7;
  const int h0 = th * 16, w0 = tw * 16;

  // stage: linear copy of pre-swizzled signs rows (gload_lds), zero invalid rows
  for (int r = wv; r < 18; r += 4) {
    int gh = h0 - 1 + r;
    char* ldst = smem + r * ROWB;
    if ((unsigned)gh < 112u) {
      const char* g = (const char*)(signs + ((size_t)(n * 112 + gh) * 114 + w0) * 64);
      gload_lds16(g + lane * 16, ldst);
      gload_lds16(g + 1024 + lane * 16, ldst + 1024);
      if (lane < 16) {
        uint4 v = *(const uint4*)(g + 2048 + lane * 16);
        *(uint4*)(ldst + 2048 + lane * 16) = v;
      }
    } else {
      uint4 z = {0, 0, 0, 0};
      *(uint4*)(ldst + lane * 16) = z;
      *(uint4*)(ldst + 1024 + lane * 16) = z;
      if (lane < 16) *(uint4*)(ldst + 2048 + lane * 16) = z;
    }
  }
  __syncthreads();

  // main loop: A = weights (M=o), B = signs (N=position). K = 9 taps x 64 c.
  f32x4 acc[4][4] = {};   // [of][pf]
  const int pw = lane & 15, kg = lane >> 4;
  const char* As = smem;
#pragma unroll
  for (int tap = 0; tap < 9; ++tap) {
    const int kh = tap / 3, kw = tap - 3 * kh;
    const int sw = pw + kw;
    const int swz = (sw & 7) << 4;
#pragma unroll
    for (int half = 0; half < 2; ++half) {
      const int cb = half * 64 + kg * 16;
      bf16x8 bf[4], af[4];
#pragma unroll
      for (int pf = 0; pf < 4; ++pf) {
        int sh = 4 * wv + pf + kh;
        bf[pf] = *(const bf16x8*)(As + (sh * 18 + sw) * 128 + (cb ^ swz));
      }
#pragma unroll
      for (int of = 0; of < 4; ++of)
        af[of] = *(const bf16x8*)(Wfrag + (((tap * 2 + half) * 4 + of) << 9) + (lane << 3));
#pragma unroll
      for (int of = 0; of < 4; ++of)
#pragma unroll
        for (int pf = 0; pf < 4; ++pf)
          acc[of][pf] = __builtin_amdgcn_mfma_f32_16x16x32_bf16(af[of], bf[pf],
                                                                acc[of][pf], 0, 0, 0);
    }
  }

  // epilogue: D row = o-in-frag = kg*4+r, col = w = pw. Direct register stores.
  float bv[4][4];
#pragma unroll
  for (int of = 0; of < 4; ++of)
#pragma unroll
    for (int r = 0; r < 4; ++r) bv[of][r] = bias[of * 16 + kg * 4 + r];
#pragma unroll
  for (int of = 0; of < 4; ++of)
#pragma unroll
    for (int pf = 0; pf < 4; ++pf) {
      size_t ob = ((size_t)(n * 64 + of * 16 + kg * 4) * 112 + (h0 + 4 * wv + pf)) * 112
                  + w0 + pw;
#pragma unroll
      for (int r = 0; r < 4; ++r)
        out[ob + (size_t)r * 12544] = fmaxf(acc[of][pf][r] + bv[of][r], 0.f);
    }
}

// ---- fallback conv (round-2 proven): reads x directly, stages+transposes in LDS
__global__ __launch_bounds__(256, 3) void conv_fallback(
    const float* __restrict__ x, const float* __restrict__ ad,
    const ushort* __restrict__ Wfrag, const float* __restrict__ bias,
    float* __restrict__ out) {
  __shared__ __align__(16) char smem[41472];
  const int tid = threadIdx.x, lane = tid & 63, wv = tid >> 6;
  int w_id = (blockIdx.x & 7) * 196 + (blockIdx.x >> 3);
  const int n = w_id / 49, t = w_id - n * 49;
  const int th = t / 7, tw = t - th * 7;
  const int h0 = th * 16, w0 = tw * 16;
  {
    const int c = tid & 63, rg = tid >> 6;
    const float a_c = ad[c], d_c = ad[64 + c];
    const float* xc = x + ((size_t)(n * 64 + c)) * 12544;
    ushort* Au = (ushort*)smem;
    for (int r = rg; r < 18; r += 4) {
      int gh = h0 - 1 + r;
      bool hok = (unsigned)gh < 112u;
      const float* xrow = xc + gh * 112;
      ushort* rowp = Au + r * (18 * 64);
#pragma unroll
      for (int sw = 0; sw < 18; ++sw) {
        int gw = w0 - 1 + sw;
        ushort v = 0;
        if (hok && (unsigned)gw < 112u) {
          float tt = fmaf(xrow[gw], a_c, d_c);
          v = (tt > 0.f) ? (ushort)0x3F80 : ((tt < 0.f) ? (ushort)0xBF80 : (ushort)0);
        }
        rowp[sw * 64 + (c ^ ((sw & 7) << 3))] = v;
      }
    }
  }
  __syncthreads();
  f32x4 acc[4][4] = {};
  const int pw = lane & 15, kg = lane >> 4;
  const char* As = smem;
#pragma unroll
  for (int tap = 0; tap < 9; ++tap) {
    const int kh = tap / 3, kw = tap - 3 * kh;
    const int sw = pw + kw;
    const int swz = (sw & 7) << 4;
#pragma unroll
    for (int half = 0; half < 2; ++half) {
      const int cb = half * 64 + kg * 16;
      bf16x8 bf[4], af[4];
#pragma unroll
      for (int pf = 0; pf < 4; ++pf) {
        int sh = 4 * wv + pf + kh;
        bf[pf] = *(const bf16x8*)(As + (sh * 18 + sw) * 128 + (cb ^ swz));
      }
#pragma unroll
      for (int of = 0; of < 4; ++of)
        af[of] = *(const bf16x8*)(Wfrag + (((tap * 2 + half) * 4 + of) << 9) + (lane << 3));
#pragma unroll
      for (int of = 0; of < 4; ++of)
#pragma unroll
        for (int pf = 0; pf < 4; ++pf)
          acc[of][pf] = __builtin_amdgcn_mfma_f32_16x16x32_bf16(af[of], bf[pf],
                                                                acc[of][pf], 0, 0, 0);
    }
  }
  float bv[4][4];
#pragma unroll
  for (int of = 0; of < 4; ++of)
#pragma unroll
    for (int r = 0; r < 4; ++r) bv[of][r] = bias[of * 16 + kg * 4 + r];
#pragma unroll
  for (int of = 0; of < 4; ++of)
#pragma unroll
    for (int pf = 0; pf < 4; ++pf) {
      size_t ob = ((size_t)(n * 64 + of * 16 + kg * 4) * 112 + (h0 + 4 * wv + pf)) * 112
                  + w0 + pw;
#pragma unroll
      for (int r = 0; r < 4; ++r)
        out[ob + (size_t)r * 12544] = fmaxf(acc[of][pf][r] + bv[of][r], 0.f);
    }
}

extern "C" void kernel_launch(void* const* d_in, const int* in_sizes, int n_in,
                              void* d_out, int out_size, void* d_ws, size_t ws_size,
                              hipStream_t stream) {
  (void)in_sizes; (void)n_in; (void)out_size;
  const float* x     = (const float*)d_in[0];
  const float* gamma = (const float*)d_in[1];
  const float* beta  = (const float*)d_in[2];
  const float* Wg    = (const float*)d_in[3];
  const float* bias  = (const float*)d_in[4];
  float* out = (float*)d_out;

  char* ws = (char*)d_ws;
  float*  ad    = (float*)ws;              // 128 f32
  double* sums  = (double*)(ws + 512);     // 128 f64
  ushort* Wfrag = (ushort*)(ws + 1536);    // 73728 B
  ushort* signs = (ushort*)(ws + 76288);   // 32*112*114*64*2 = 52,297,728 B
  const size_t need = 76288 + (size_t)32 * 112 * 114 * 128;

  hipMemsetAsync(sums, 0, 128 * sizeof(double), stream);
  prep_weights<<<dim3(144), dim3(256), 0, stream>>>(Wg, Wfrag);
  stats_kernel<<<dim3(2048), dim3(256), 0, stream>>>(x, sums);
  finalize_kernel<<<dim3(1), dim3(64), 0, stream>>>(sums, gamma, beta, ad);
  if (ws_size >= need) {
    binarize_kernel<<<dim3(112, 32), dim3(256), 0, stream>>>(x, ad, signs);
    conv_kernel<<<dim3(1568), dim3(256), 0, stream>>>(signs, Wfrag, bias, out);
  } else {
    conv_fallback<<<dim3(1568), dim3(256), 0, stream>>>(x, ad, Wfrag, bias, out);
  }
}